// Round 3
// baseline (486.932 us; speedup 1.0000x reference)
//
#include <hip/hip_runtime.h>

// uDTW forward DP, R11: two batches per block (restore 2 waves/SIMD latency
// hiding that R10 lost) + parity-split boundary planes (kill the 4-way store
// bank conflict R10's 8B-stride b32 publish had).
//
// R10 post-mortem: the A/B "ILP-2" chains are cross-coupled into ONE
// serpentine chain (newEA -> sumB -> newEB -> DPP -> sEA -> newEA), so R10
// kept R9's ~28cyc/step latency chain but dropped to 1 wave/SIMD -> per-CU
// VALUBusy fell 35.6% -> 24.6%, per-phase cost rose 7.4k -> 11.3k cycles.
//
// R11 structure: 512 threads = 8 waves; h = t>>8 selects batch 2*bid+h,
// local lane tl = t&255, local wave w = tl>>6 (0..3). Waves i and i+4 land
// on the same SIMD -> two independent serpentine chains interleave -> latency
// hidden. Both halves have identical phase schedules, so the block-wide
// __syncthreads costs nothing extra. PHASES = 35, per-wave code = R10.
//
// Publish: stored column parity is lane-invariant (c = cA0-1+kk, cA0 even),
// so split E/D planes by column parity -> each b32 store has -4B lane stride
// = 2 lanes/bank = free (m136). Consumer reads are wave-uniform float4
// broadcasts from the half-planes (ebase/2 stays 16B-aligned); step wiring
// reorders macro args at zero cost.

constexpr int N = 512;
constexpr int M = 512;
constexpr int BATCH = 32;
constexpr int NM = N + M;                  // 1024; diags d = 2..NM
constexpr int K = 32;                      // diagonals per burst
constexpr int NB = 32;                     // bursts cover d = 2..1025
constexpr int PHASES = NB + 3;             // 35
constexpr float NL2E = -1.4426950408889634f;   // -log2(e)
constexpr float NLN2 = -0.6931471805599453f;   // -ln(2)
constexpr float EPS  = 1e-30f;

__device__ __forceinline__ float lane_shr1_or(float oldv, float x) {
  // lane n gets lane n-1's x; lane 0 keeps oldv (bound_ctrl=false).
  return __int_as_float(__builtin_amdgcn_update_dpp(
      __float_as_int(oldv), __float_as_int(x), 0x138, 0xf, 0xf, false));
}
__device__ __forceinline__ int qclamp(int q) {
  return q < 0 ? 0 : (q > 127 ? 127 : q);
}

__global__ __launch_bounds__(512, 1)
void softdtw_fwd(const float* __restrict__ D,
                 const float* __restrict__ Sig,
                 float* __restrict__ out) {
  const int t  = threadIdx.x;          // 0..511
  const int h  = t >> 8;               // batch half 0/1
  const int tl = t & 255;              // local lane: owns rows 2tl, 2tl+1
  const int w  = tl >> 6;              // local wave 0..3
  const int b  = 2 * blockIdx.x + h;

  const float4* DrowA4 = (const float4*)(D + ((size_t)b * N + 2 * tl) * M);
  const float4* DrowB4 = (const float4*)(D + ((size_t)b * N + 2 * tl + 1) * M);

  // boundary planes, split by column parity. Original index I = 128 + c
  // (c = j-1, 128-halo). I odd -> *Odd[(I-1)/2], I even -> *Even[I/2].
  __shared__ float eOdd [2][4][384];
  __shared__ float eEven[2][4][384];
  __shared__ float dOdd [2][4][384];
  __shared__ float dEven[2][4][384];
  {
    float* z0 = &eOdd[0][0][0];  float* z1 = &eEven[0][0][0];
    float* z2 = &dOdd[0][0][0];  float* z3 = &dEven[0][0][0];
    for (int idx = t; idx < 2 * 4 * 384; idx += 512) {
      z0[idx] = 0.f; z1[idx] = 0.f; z2[idx] = 0.f; z3[idx] = 0.f;
    }
  }

  // carried state (D values pre-scaled by NL2E; carried/published raw,
  // consumers multiply by masked-zero E)
  float eSelfA = 0.f, dSelfA = 0.f;            // row A at prev diag
  float eA1 = 0.f, dA1 = 0.f;                  // row A, one step further back
  float eN2A = (tl == 0) ? 1.f : 0.f;          // neighbor (i-1) at d-2; E(0,0)=1
  float dN2A = 0.f;
  float eSelfB = 0.f, dSelfB = 0.f;            // row B at prev diag

  // Sig contributes only via 4 elements at the final cell (row B of tl=255)
  float sgA = 0.f, sg0 = 0.f, sg1 = 0.f, sg2 = 0.f;
  if (tl == 255) {
    const float* Sb = Sig + (size_t)b * N * M;
    sgA = Sb[(size_t)(N - 1) * M + (M - 1)];
    sg0 = Sb[(size_t)(N - 2) * M + (M - 2)];
    sg1 = Sb[(size_t)(N - 2) * M + (M - 1)];
    sg2 = Sb[(size_t)(N - 1) * M + (M - 2)];
  }

  const int Bl = 4 * w, Bh = 4 * w + 19;   // active bursts for this wave
  const bool sA2 = (tl & 1) != 0;          // row-A funnel: shift {0,2}
  const bool sB2 = (tl & 1) == 0;          // row-B funnel: shift {1,3}

  // current-burst D windows: 9 quads per row
  float4 u0,u1,u2,u3,u4,u5,u6,u7,u8;       // row A
  float4 v0,v1,v2,v3,v4,v5,v6,v7,v8;       // row B
  {
    const int qa = (32 * Bl - 2 * tl) >> 2;
    u0 = DrowA4[qclamp(qa + 0)]; u1 = DrowA4[qclamp(qa + 1)];
    u2 = DrowA4[qclamp(qa + 2)]; u3 = DrowA4[qclamp(qa + 3)];
    u4 = DrowA4[qclamp(qa + 4)]; u5 = DrowA4[qclamp(qa + 5)];
    u6 = DrowA4[qclamp(qa + 6)]; u7 = DrowA4[qclamp(qa + 7)];
    u8 = DrowA4[qclamp(qa + 8)];
    const int qb = (32 * Bl - 2 * tl - 1) >> 2;
    v0 = DrowB4[qclamp(qb + 0)]; v1 = DrowB4[qclamp(qb + 1)];
    v2 = DrowB4[qclamp(qb + 2)]; v3 = DrowB4[qclamp(qb + 3)];
    v4 = DrowB4[qclamp(qb + 4)]; v5 = DrowB4[qclamp(qb + 5)];
    v6 = DrowB4[qclamp(qb + 6)]; v7 = DrowB4[qclamp(qb + 7)];
    v8 = DrowB4[qclamp(qb + 8)];
  }
  __syncthreads();

  for (int p = 0; p < PHASES; ++p) {
    const int B = p - w;
    const int nB = B + 1;
    const bool dopre = (nB >= Bl) && (nB <= Bh);   // wave-uniform

    // ---- prefetch next burst's D quads (consumed after the barrier)
    float4 pu0,pu1,pu2,pu3,pu4,pu5,pu6,pu7,pu8;
    float4 pv0,pv1,pv2,pv3,pv4,pv5,pv6,pv7,pv8;
    if (dopre) {
      const int qa = (32 * nB - 2 * tl) >> 2;
      pu0 = DrowA4[qclamp(qa + 0)]; pu1 = DrowA4[qclamp(qa + 1)];
      pu2 = DrowA4[qclamp(qa + 2)]; pu3 = DrowA4[qclamp(qa + 3)];
      pu4 = DrowA4[qclamp(qa + 4)]; pu5 = DrowA4[qclamp(qa + 5)];
      pu6 = DrowA4[qclamp(qa + 6)]; pu7 = DrowA4[qclamp(qa + 7)];
      pu8 = DrowA4[qclamp(qa + 8)];
      const int qb = (32 * nB - 2 * tl - 1) >> 2;
      pv0 = DrowB4[qclamp(qb + 0)]; pv1 = DrowB4[qclamp(qb + 1)];
      pv2 = DrowB4[qclamp(qb + 2)]; pv3 = DrowB4[qclamp(qb + 3)];
      pv4 = DrowB4[qclamp(qb + 4)]; pv5 = DrowB4[qclamp(qb + 5)];
      pv6 = DrowB4[qclamp(qb + 6)]; pv7 = DrowB4[qclamp(qb + 7)];
      pv8 = DrowB4[qclamp(qb + 8)];
    }

    if (B >= Bl && B <= Bh) {
      const int d0 = 2 + B * K;
      const int cA0 = 32 * B - 2 * tl;   // row-A column index base (c = j-1)

      // ---- neighbor boundary preload (wave-uniform broadcast reads):
      // need E[I], D[I] for I = ebase..ebase+31, ebase = 32B-128w+128 (even).
      // half-index base hb = ebase/2 = 16B-64w+64, 16B-aligned.
      float4 mEe0,mEe1,mEe2,mEe3, mEo0,mEo1,mEo2,mEo3;
      float4 mDe0,mDe1,mDe2,mDe3, mDo0,mDo1,mDo2,mDo3;
      if (w > 0) {
        const int hb = 16 * B - 64 * w + 64;
        const float4* pe = (const float4*)&eEven[h][w - 1][hb];
        const float4* po = (const float4*)&eOdd [h][w - 1][hb];
        const float4* qe = (const float4*)&dEven[h][w - 1][hb];
        const float4* qo = (const float4*)&dOdd [h][w - 1][hb];
        mEe0 = pe[0]; mEe1 = pe[1]; mEe2 = pe[2]; mEe3 = pe[3];
        mEo0 = po[0]; mEo1 = po[1]; mEo2 = po[2]; mEo3 = po[3];
        mDe0 = qe[0]; mDe1 = qe[1]; mDe2 = qe[2]; mDe3 = qe[3];
        mDo0 = qo[0]; mDo1 = qo[1]; mDo2 = qo[2]; mDo3 = qo[3];
      } else {
        const float4 z = make_float4(0.f, 0.f, 0.f, 0.f);
        mEe0=z;mEe1=z;mEe2=z;mEe3=z; mEo0=z;mEo1=z;mEo2=z;mEo3=z;
        mDe0=z;mDe1=z;mDe2=z;mDe3=z; mDo0=z;mDo1=z;mDo2=z;mDo3=z;
      }

      // ---- unpack windows
      const float
        A0=u0.x, A1=u0.y, A2=u0.z, A3=u0.w,  A4=u1.x, A5=u1.y, A6=u1.z, A7=u1.w,
        A8=u2.x, A9=u2.y, A10=u2.z, A11=u2.w, A12=u3.x, A13=u3.y, A14=u3.z, A15=u3.w,
        A16=u4.x, A17=u4.y, A18=u4.z, A19=u4.w, A20=u5.x, A21=u5.y, A22=u5.z, A23=u5.w,
        A24=u6.x, A25=u6.y, A26=u6.z, A27=u6.w, A28=u7.x, A29=u7.y, A30=u7.z, A31=u7.w,
        A32=u8.x, A33=u8.y;
      const float
        F1=v0.y, F2=v0.z, F3=v0.w,  F4=v1.x, F5=v1.y, F6=v1.z, F7=v1.w,
        F8=v2.x, F9=v2.y, F10=v2.z, F11=v2.w, F12=v3.x, F13=v3.y, F14=v3.z, F15=v3.w,
        F16=v4.x, F17=v4.y, F18=v4.z, F19=v4.w, F20=v5.x, F21=v5.y, F22=v5.z, F23=v5.w,
        F24=v6.x, F25=v6.y, F26=v6.z, F27=v6.w, F28=v7.x, F29=v7.y, F30=v7.z, F31=v7.w,
        F32=v8.x, F33=v8.y, F34=v8.z;

      // ---- funnel align: gA_k = D_A[cA0+k], gB_k = D_B[cA0-1+k]
      const float
        gA0 =sA2?A2 :A0,  gA1 =sA2?A3 :A1,  gA2 =sA2?A4 :A2,  gA3 =sA2?A5 :A3,
        gA4 =sA2?A6 :A4,  gA5 =sA2?A7 :A5,  gA6 =sA2?A8 :A6,  gA7 =sA2?A9 :A7,
        gA8 =sA2?A10:A8,  gA9 =sA2?A11:A9,  gA10=sA2?A12:A10, gA11=sA2?A13:A11,
        gA12=sA2?A14:A12, gA13=sA2?A15:A13, gA14=sA2?A16:A14, gA15=sA2?A17:A15,
        gA16=sA2?A18:A16, gA17=sA2?A19:A17, gA18=sA2?A20:A18, gA19=sA2?A21:A19,
        gA20=sA2?A22:A20, gA21=sA2?A23:A21, gA22=sA2?A24:A22, gA23=sA2?A25:A23,
        gA24=sA2?A26:A24, gA25=sA2?A27:A25, gA26=sA2?A28:A26, gA27=sA2?A29:A27,
        gA28=sA2?A30:A28, gA29=sA2?A31:A29, gA30=sA2?A32:A30, gA31=sA2?A33:A31;
      const float
        gB0 =sB2?F3 :F1,  gB1 =sB2?F4 :F2,  gB2 =sB2?F5 :F3,  gB3 =sB2?F6 :F4,
        gB4 =sB2?F7 :F5,  gB5 =sB2?F8 :F6,  gB6 =sB2?F9 :F7,  gB7 =sB2?F10:F8,
        gB8 =sB2?F11:F9,  gB9 =sB2?F12:F10, gB10=sB2?F13:F11, gB11=sB2?F14:F12,
        gB12=sB2?F15:F13, gB13=sB2?F16:F14, gB14=sB2?F17:F15, gB15=sB2?F18:F16,
        gB16=sB2?F19:F17, gB17=sB2?F20:F18, gB18=sB2?F21:F19, gB19=sB2?F22:F20,
        gB20=sB2?F23:F21, gB21=sB2?F24:F22, gB22=sB2?F25:F23, gB23=sB2?F26:F24,
        gB24=sB2?F27:F25, gB25=sB2?F28:F26, gB26=sB2?F29:F27, gB27=sB2?F30:F28,
        gB28=sB2?F31:F29, gB29=sB2?F32:F30, gB30=sB2?F33:F31, gB31=sB2?F34:F32;

      // publish pointers: stored column c = cA0-1+kk, I = 128+c.
      // kk even -> I odd  -> *Odd [63 + 16B - tl + kk/2]
      // kk odd  -> I even -> *Even[64 + 16B - tl + (kk-1)/2]
      // lane stride -4B per plane => 2 lanes/bank = conflict-free.
      const int sb = 16 * B - tl;
      float* pEo = &eOdd [h][w][63 + sb];
      float* pEe = &eEven[h][w][64 + sb];
      float* pDo = &dOdd [h][w][63 + sb];
      float* pDe = &dEven[h][w][64 + sb];

#define STEP(kk, NEv, NDv, GA, GB, PE_, PD_, ix)                              \
      {                                                                       \
        const float eA0v = eSelfA, dA0v = dSelfA;                             \
        const float eB0v = eSelfB, dB0v = dSelfB;                             \
        const int cA = cA0 + (kk);                                            \
        const float ddLA = (GA) * NL2E;                                       \
        const float ddLAm = ((unsigned)cA < 512u) ? ddLA : -1e30f;            \
        const float ddLB = (GB) * NL2E;                                       \
        const float ddLBm = ((unsigned)(cA - 1) < 512u) ? ddLB : -1e30f;      \
        const float sEA = lane_shr1_or((NEv), eB0v);                          \
        const float sDA = lane_shr1_or((NDv), dB0v);                          \
        const float sumA = ((eN2A + eA0v) + EPS) + sEA;                       \
        const float invA = __builtin_amdgcn_rcpf(sumA);                       \
        const float numA = fmaf(eN2A, dN2A, fmaf(sEA, sDA, eA0v * dA0v));     \
        const float rrA = fmaf(invA, numA, ddLAm);                            \
        const float newEA = __builtin_amdgcn_exp2f(rrA);                      \
        const float sumB = ((eA1 + eB0v) + EPS) + eA0v;                       \
        const float invB = __builtin_amdgcn_rcpf(sumB);                       \
        const float numB = fmaf(eA1, dA1, fmaf(eA0v, dA0v, eB0v * dB0v));     \
        const float rrB = fmaf(invB, numB, ddLBm);                            \
        const float newEB = __builtin_amdgcn_exp2f(rrB);                      \
        if (d0 + (kk) == NM && tl == 255) {                                   \
          out[b] = rrB * NLN2;                                                \
          out[BATCH + b] = sgA + invB * (eA1 * sg0 + eA0v * sg1 + eB0v * sg2);\
        }                                                                     \
        eN2A = sEA; dN2A = sDA;                                               \
        eA1 = eA0v; dA1 = dA0v;                                               \
        eSelfA = newEA; dSelfA = ddLA;                                        \
        eSelfB = newEB; dSelfB = ddLB;                                        \
        PE_[ix] = newEB;                                                      \
        PD_[ix] = ddLB;                                                       \
      }

      // neighbor source: I = ebase+kk; kk even -> Even[hb+kk/2],
      // kk odd -> Odd[hb+(kk-1)/2]
      STEP(0,  mEe0.x, mDe0.x, gA0,  gB0,  pEo, pDo, 0)
      STEP(1,  mEo0.x, mDo0.x, gA1,  gB1,  pEe, pDe, 0)
      STEP(2,  mEe0.y, mDe0.y, gA2,  gB2,  pEo, pDo, 1)
      STEP(3,  mEo0.y, mDo0.y, gA3,  gB3,  pEe, pDe, 1)
      STEP(4,  mEe0.z, mDe0.z, gA4,  gB4,  pEo, pDo, 2)
      STEP(5,  mEo0.z, mDo0.z, gA5,  gB5,  pEe, pDe, 2)
      STEP(6,  mEe0.w, mDe0.w, gA6,  gB6,  pEo, pDo, 3)
      STEP(7,  mEo0.w, mDo0.w, gA7,  gB7,  pEe, pDe, 3)
      STEP(8,  mEe1.x, mDe1.x, gA8,  gB8,  pEo, pDo, 4)
      STEP(9,  mEo1.x, mDo1.x, gA9,  gB9,  pEe, pDe, 4)
      STEP(10, mEe1.y, mDe1.y, gA10, gB10, pEo, pDo, 5)
      STEP(11, mEo1.y, mDo1.y, gA11, gB11, pEe, pDe, 5)
      STEP(12, mEe1.z, mDe1.z, gA12, gB12, pEo, pDo, 6)
      STEP(13, mEo1.z, mDo1.z, gA13, gB13, pEe, pDe, 6)
      STEP(14, mEe1.w, mDe1.w, gA14, gB14, pEo, pDo, 7)
      STEP(15, mEo1.w, mDo1.w, gA15, gB15, pEe, pDe, 7)
      STEP(16, mEe2.x, mDe2.x, gA16, gB16, pEo, pDo, 8)
      STEP(17, mEo2.x, mDo2.x, gA17, gB17, pEe, pDe, 8)
      STEP(18, mEe2.y, mDe2.y, gA18, gB18, pEo, pDo, 9)
      STEP(19, mEo2.y, mDo2.y, gA19, gB19, pEe, pDe, 9)
      STEP(20, mEe2.z, mDe2.z, gA20, gB20, pEo, pDo, 10)
      STEP(21, mEo2.z, mDo2.z, gA21, gB21, pEe, pDe, 10)
      STEP(22, mEe2.w, mDe2.w, gA22, gB22, pEo, pDo, 11)
      STEP(23, mEo2.w, mDo2.w, gA23, gB23, pEe, pDe, 11)
      STEP(24, mEe3.x, mDe3.x, gA24, gB24, pEo, pDo, 12)
      STEP(25, mEo3.x, mDo3.x, gA25, gB25, pEe, pDe, 12)
      STEP(26, mEe3.y, mDe3.y, gA26, gB26, pEo, pDo, 13)
      STEP(27, mEo3.y, mDo3.y, gA27, gB27, pEe, pDe, 13)
      STEP(28, mEe3.z, mDe3.z, gA28, gB28, pEo, pDo, 14)
      STEP(29, mEo3.z, mDo3.z, gA29, gB29, pEe, pDe, 14)
      STEP(30, mEe3.w, mDe3.w, gA30, gB30, pEo, pDo, 15)
      STEP(31, mEo3.w, mDo3.w, gA31, gB31, pEe, pDe, 15)
#undef STEP
    }

    // rotate in the prefetched windows (waitcnt lands here, far from issue)
    if (dopre) {
      u0 = pu0; u1 = pu1; u2 = pu2; u3 = pu3; u4 = pu4;
      u5 = pu5; u6 = pu6; u7 = pu7; u8 = pu8;
      v0 = pv0; v1 = pv1; v2 = pv2; v3 = pv3; v4 = pv4;
      v5 = pv5; v6 = pv6; v7 = pv7; v8 = pv8;
    }
    __syncthreads();
  }
}

extern "C" void kernel_launch(void* const* d_in, const int* in_sizes, int n_in,
                              void* d_out, int out_size, void* d_ws, size_t ws_size,
                              hipStream_t stream) {
  const float* D   = (const float*)d_in[0];
  const float* Sig = (const float*)d_in[1];
  float* out = (float*)d_out;
  softdtw_fwd<<<dim3(BATCH / 2), dim3(512), 0, stream>>>(D, Sig, out);
}

// Round 4
// 430.619 us; speedup vs baseline: 1.1308x; 1.1308x over previous
//
#include <hip/hip_runtime.h>

// uDTW forward DP, R12 = R11 + amdgpu_waves_per_eu(2,2) pin.
//
// R11 post-mortem: __launch_bounds__(512,1) only sets MIN waves/EU=1; the
// allocator targeted its default 4 waves/EU -> capped VGPR at exactly 128
// (=512/4) and spilled the ~150-reg working set. Evidence: WRITE_SIZE
// 2KB -> 1473KB (scratch stores; kernel only writes 256B of results),
// VALUBusy 0.15% (scratch round-trips inside the serpentine chain).
// The parity-split publish DID work: SQ_LDS_BANK_CONFLICT 327680 -> 0.
//
// R12: pin min=max=2 waves/EU -> VGPR budget 512/2 = 256 >= the ~150 the
// body needs -> no spill. An 8-wave block forces 2 waves/SIMD residency
// anyway (grid=16, 1 block/CU), so max=2 costs nothing.
//
// Structure (unchanged from R11): 512 threads = 8 waves; h = t>>8 selects
// batch 2*bid+h, local lane tl = t&255, local wave w = tl>>6. Each SIMD
// hosts two waves with independent serpentine chains -> latency hiding at
// R9 level with R10's shorter phases (35) and halved per-cell DPP/funnel.
// Publish: E/D planes split by column parity -> -4B lane stride b32 stores
// = 2 lanes/bank = conflict-free; consumer reads are wave-uniform float4
// broadcasts.

constexpr int N = 512;
constexpr int M = 512;
constexpr int BATCH = 32;
constexpr int NM = N + M;                  // 1024; diags d = 2..NM
constexpr int K = 32;                      // diagonals per burst
constexpr int NB = 32;                     // bursts cover d = 2..1025
constexpr int PHASES = NB + 3;             // 35
constexpr float NL2E = -1.4426950408889634f;   // -log2(e)
constexpr float NLN2 = -0.6931471805599453f;   // -ln(2)
constexpr float EPS  = 1e-30f;

__device__ __forceinline__ float lane_shr1_or(float oldv, float x) {
  // lane n gets lane n-1's x; lane 0 keeps oldv (bound_ctrl=false).
  return __int_as_float(__builtin_amdgcn_update_dpp(
      __float_as_int(oldv), __float_as_int(x), 0x138, 0xf, 0xf, false));
}
__device__ __forceinline__ int qclamp(int q) {
  return q < 0 ? 0 : (q > 127 ? 127 : q);
}

__global__ __launch_bounds__(512) __attribute__((amdgpu_waves_per_eu(2, 2)))
void softdtw_fwd(const float* __restrict__ D,
                 const float* __restrict__ Sig,
                 float* __restrict__ out) {
  const int t  = threadIdx.x;          // 0..511
  const int h  = t >> 8;               // batch half 0/1
  const int tl = t & 255;              // local lane: owns rows 2tl, 2tl+1
  const int w  = tl >> 6;              // local wave 0..3
  const int b  = 2 * blockIdx.x + h;

  const float4* DrowA4 = (const float4*)(D + ((size_t)b * N + 2 * tl) * M);
  const float4* DrowB4 = (const float4*)(D + ((size_t)b * N + 2 * tl + 1) * M);

  // boundary planes, split by column parity. Original index I = 128 + c
  // (c = j-1, 128-halo). I odd -> *Odd[(I-1)/2], I even -> *Even[I/2].
  __shared__ float eOdd [2][4][384];
  __shared__ float eEven[2][4][384];
  __shared__ float dOdd [2][4][384];
  __shared__ float dEven[2][4][384];
  {
    float* z0 = &eOdd[0][0][0];  float* z1 = &eEven[0][0][0];
    float* z2 = &dOdd[0][0][0];  float* z3 = &dEven[0][0][0];
    for (int idx = t; idx < 2 * 4 * 384; idx += 512) {
      z0[idx] = 0.f; z1[idx] = 0.f; z2[idx] = 0.f; z3[idx] = 0.f;
    }
  }

  // carried state (D values pre-scaled by NL2E; carried/published raw,
  // consumers multiply by masked-zero E)
  float eSelfA = 0.f, dSelfA = 0.f;            // row A at prev diag
  float eA1 = 0.f, dA1 = 0.f;                  // row A, one step further back
  float eN2A = (tl == 0) ? 1.f : 0.f;          // neighbor (i-1) at d-2; E(0,0)=1
  float dN2A = 0.f;
  float eSelfB = 0.f, dSelfB = 0.f;            // row B at prev diag

  // Sig contributes only via 4 elements at the final cell (row B of tl=255)
  float sgA = 0.f, sg0 = 0.f, sg1 = 0.f, sg2 = 0.f;
  if (tl == 255) {
    const float* Sb = Sig + (size_t)b * N * M;
    sgA = Sb[(size_t)(N - 1) * M + (M - 1)];
    sg0 = Sb[(size_t)(N - 2) * M + (M - 2)];
    sg1 = Sb[(size_t)(N - 2) * M + (M - 1)];
    sg2 = Sb[(size_t)(N - 1) * M + (M - 2)];
  }

  const int Bl = 4 * w, Bh = 4 * w + 19;   // active bursts for this wave
  const bool sA2 = (tl & 1) != 0;          // row-A funnel: shift {0,2}
  const bool sB2 = (tl & 1) == 0;          // row-B funnel: shift {1,3}

  // current-burst D windows: 9 quads per row
  float4 u0,u1,u2,u3,u4,u5,u6,u7,u8;       // row A
  float4 v0,v1,v2,v3,v4,v5,v6,v7,v8;       // row B
  {
    const int qa = (32 * Bl - 2 * tl) >> 2;
    u0 = DrowA4[qclamp(qa + 0)]; u1 = DrowA4[qclamp(qa + 1)];
    u2 = DrowA4[qclamp(qa + 2)]; u3 = DrowA4[qclamp(qa + 3)];
    u4 = DrowA4[qclamp(qa + 4)]; u5 = DrowA4[qclamp(qa + 5)];
    u6 = DrowA4[qclamp(qa + 6)]; u7 = DrowA4[qclamp(qa + 7)];
    u8 = DrowA4[qclamp(qa + 8)];
    const int qb = (32 * Bl - 2 * tl - 1) >> 2;
    v0 = DrowB4[qclamp(qb + 0)]; v1 = DrowB4[qclamp(qb + 1)];
    v2 = DrowB4[qclamp(qb + 2)]; v3 = DrowB4[qclamp(qb + 3)];
    v4 = DrowB4[qclamp(qb + 4)]; v5 = DrowB4[qclamp(qb + 5)];
    v6 = DrowB4[qclamp(qb + 6)]; v7 = DrowB4[qclamp(qb + 7)];
    v8 = DrowB4[qclamp(qb + 8)];
  }
  __syncthreads();

  for (int p = 0; p < PHASES; ++p) {
    const int B = p - w;
    const int nB = B + 1;
    const bool dopre = (nB >= Bl) && (nB <= Bh);   // wave-uniform

    // ---- prefetch next burst's D quads (consumed after the barrier)
    float4 pu0,pu1,pu2,pu3,pu4,pu5,pu6,pu7,pu8;
    float4 pv0,pv1,pv2,pv3,pv4,pv5,pv6,pv7,pv8;
    if (dopre) {
      const int qa = (32 * nB - 2 * tl) >> 2;
      pu0 = DrowA4[qclamp(qa + 0)]; pu1 = DrowA4[qclamp(qa + 1)];
      pu2 = DrowA4[qclamp(qa + 2)]; pu3 = DrowA4[qclamp(qa + 3)];
      pu4 = DrowA4[qclamp(qa + 4)]; pu5 = DrowA4[qclamp(qa + 5)];
      pu6 = DrowA4[qclamp(qa + 6)]; pu7 = DrowA4[qclamp(qa + 7)];
      pu8 = DrowA4[qclamp(qa + 8)];
      const int qb = (32 * nB - 2 * tl - 1) >> 2;
      pv0 = DrowB4[qclamp(qb + 0)]; pv1 = DrowB4[qclamp(qb + 1)];
      pv2 = DrowB4[qclamp(qb + 2)]; pv3 = DrowB4[qclamp(qb + 3)];
      pv4 = DrowB4[qclamp(qb + 4)]; pv5 = DrowB4[qclamp(qb + 5)];
      pv6 = DrowB4[qclamp(qb + 6)]; pv7 = DrowB4[qclamp(qb + 7)];
      pv8 = DrowB4[qclamp(qb + 8)];
    }

    if (B >= Bl && B <= Bh) {
      const int d0 = 2 + B * K;
      const int cA0 = 32 * B - 2 * tl;   // row-A column index base (c = j-1)

      // ---- neighbor boundary preload (wave-uniform broadcast reads):
      // need E[I], D[I] for I = ebase..ebase+31, ebase = 32B-128w+128 (even).
      // half-index base hb = ebase/2 = 16B-64w+64, 16B-aligned.
      float4 mEe0,mEe1,mEe2,mEe3, mEo0,mEo1,mEo2,mEo3;
      float4 mDe0,mDe1,mDe2,mDe3, mDo0,mDo1,mDo2,mDo3;
      if (w > 0) {
        const int hb = 16 * B - 64 * w + 64;
        const float4* pe = (const float4*)&eEven[h][w - 1][hb];
        const float4* po = (const float4*)&eOdd [h][w - 1][hb];
        const float4* qe = (const float4*)&dEven[h][w - 1][hb];
        const float4* qo = (const float4*)&dOdd [h][w - 1][hb];
        mEe0 = pe[0]; mEe1 = pe[1]; mEe2 = pe[2]; mEe3 = pe[3];
        mEo0 = po[0]; mEo1 = po[1]; mEo2 = po[2]; mEo3 = po[3];
        mDe0 = qe[0]; mDe1 = qe[1]; mDe2 = qe[2]; mDe3 = qe[3];
        mDo0 = qo[0]; mDo1 = qo[1]; mDo2 = qo[2]; mDo3 = qo[3];
      } else {
        const float4 z = make_float4(0.f, 0.f, 0.f, 0.f);
        mEe0=z;mEe1=z;mEe2=z;mEe3=z; mEo0=z;mEo1=z;mEo2=z;mEo3=z;
        mDe0=z;mDe1=z;mDe2=z;mDe3=z; mDo0=z;mDo1=z;mDo2=z;mDo3=z;
      }

      // ---- unpack windows
      const float
        A0=u0.x, A1=u0.y, A2=u0.z, A3=u0.w,  A4=u1.x, A5=u1.y, A6=u1.z, A7=u1.w,
        A8=u2.x, A9=u2.y, A10=u2.z, A11=u2.w, A12=u3.x, A13=u3.y, A14=u3.z, A15=u3.w,
        A16=u4.x, A17=u4.y, A18=u4.z, A19=u4.w, A20=u5.x, A21=u5.y, A22=u5.z, A23=u5.w,
        A24=u6.x, A25=u6.y, A26=u6.z, A27=u6.w, A28=u7.x, A29=u7.y, A30=u7.z, A31=u7.w,
        A32=u8.x, A33=u8.y;
      const float
        F1=v0.y, F2=v0.z, F3=v0.w,  F4=v1.x, F5=v1.y, F6=v1.z, F7=v1.w,
        F8=v2.x, F9=v2.y, F10=v2.z, F11=v2.w, F12=v3.x, F13=v3.y, F14=v3.z, F15=v3.w,
        F16=v4.x, F17=v4.y, F18=v4.z, F19=v4.w, F20=v5.x, F21=v5.y, F22=v5.z, F23=v5.w,
        F24=v6.x, F25=v6.y, F26=v6.z, F27=v6.w, F28=v7.x, F29=v7.y, F30=v7.z, F31=v7.w,
        F32=v8.x, F33=v8.y, F34=v8.z;

      // ---- funnel align: gA_k = D_A[cA0+k], gB_k = D_B[cA0-1+k]
      const float
        gA0 =sA2?A2 :A0,  gA1 =sA2?A3 :A1,  gA2 =sA2?A4 :A2,  gA3 =sA2?A5 :A3,
        gA4 =sA2?A6 :A4,  gA5 =sA2?A7 :A5,  gA6 =sA2?A8 :A6,  gA7 =sA2?A9 :A7,
        gA8 =sA2?A10:A8,  gA9 =sA2?A11:A9,  gA10=sA2?A12:A10, gA11=sA2?A13:A11,
        gA12=sA2?A14:A12, gA13=sA2?A15:A13, gA14=sA2?A16:A14, gA15=sA2?A17:A15,
        gA16=sA2?A18:A16, gA17=sA2?A19:A17, gA18=sA2?A20:A18, gA19=sA2?A21:A19,
        gA20=sA2?A22:A20, gA21=sA2?A23:A21, gA22=sA2?A24:A22, gA23=sA2?A25:A23,
        gA24=sA2?A26:A24, gA25=sA2?A27:A25, gA26=sA2?A28:A26, gA27=sA2?A29:A27,
        gA28=sA2?A30:A28, gA29=sA2?A31:A29, gA30=sA2?A32:A30, gA31=sA2?A33:A31;
      const float
        gB0 =sB2?F3 :F1,  gB1 =sB2?F4 :F2,  gB2 =sB2?F5 :F3,  gB3 =sB2?F6 :F4,
        gB4 =sB2?F7 :F5,  gB5 =sB2?F8 :F6,  gB6 =sB2?F9 :F7,  gB7 =sB2?F10:F8,
        gB8 =sB2?F11:F9,  gB9 =sB2?F12:F10, gB10=sB2?F13:F11, gB11=sB2?F14:F12,
        gB12=sB2?F15:F13, gB13=sB2?F16:F14, gB14=sB2?F17:F15, gB15=sB2?F18:F16,
        gB16=sB2?F19:F17, gB17=sB2?F20:F18, gB18=sB2?F21:F19, gB19=sB2?F22:F20,
        gB20=sB2?F23:F21, gB21=sB2?F24:F22, gB22=sB2?F25:F23, gB23=sB2?F26:F24,
        gB24=sB2?F27:F25, gB25=sB2?F28:F26, gB26=sB2?F29:F27, gB27=sB2?F30:F28,
        gB28=sB2?F31:F29, gB29=sB2?F32:F30, gB30=sB2?F33:F31, gB31=sB2?F34:F32;

      // publish pointers: stored column c = cA0-1+kk, I = 128+c.
      // kk even -> I odd  -> *Odd [63 + 16B - tl + kk/2]
      // kk odd  -> I even -> *Even[64 + 16B - tl + (kk-1)/2]
      // lane stride -4B per plane => 2 lanes/bank = conflict-free.
      const int sb = 16 * B - tl;
      float* pEo = &eOdd [h][w][63 + sb];
      float* pEe = &eEven[h][w][64 + sb];
      float* pDo = &dOdd [h][w][63 + sb];
      float* pDe = &dEven[h][w][64 + sb];

#define STEP(kk, NEv, NDv, GA, GB, PE_, PD_, ix)                              \
      {                                                                       \
        const float eA0v = eSelfA, dA0v = dSelfA;                             \
        const float eB0v = eSelfB, dB0v = dSelfB;                             \
        const int cA = cA0 + (kk);                                            \
        const float ddLA = (GA) * NL2E;                                       \
        const float ddLAm = ((unsigned)cA < 512u) ? ddLA : -1e30f;            \
        const float ddLB = (GB) * NL2E;                                       \
        const float ddLBm = ((unsigned)(cA - 1) < 512u) ? ddLB : -1e30f;      \
        const float sEA = lane_shr1_or((NEv), eB0v);                          \
        const float sDA = lane_shr1_or((NDv), dB0v);                          \
        const float sumA = ((eN2A + eA0v) + EPS) + sEA;                       \
        const float invA = __builtin_amdgcn_rcpf(sumA);                       \
        const float numA = fmaf(eN2A, dN2A, fmaf(sEA, sDA, eA0v * dA0v));     \
        const float rrA = fmaf(invA, numA, ddLAm);                            \
        const float newEA = __builtin_amdgcn_exp2f(rrA);                      \
        const float sumB = ((eA1 + eB0v) + EPS) + eA0v;                       \
        const float invB = __builtin_amdgcn_rcpf(sumB);                       \
        const float numB = fmaf(eA1, dA1, fmaf(eA0v, dA0v, eB0v * dB0v));     \
        const float rrB = fmaf(invB, numB, ddLBm);                            \
        const float newEB = __builtin_amdgcn_exp2f(rrB);                      \
        if (d0 + (kk) == NM && tl == 255) {                                   \
          out[b] = rrB * NLN2;                                                \
          out[BATCH + b] = sgA + invB * (eA1 * sg0 + eA0v * sg1 + eB0v * sg2);\
        }                                                                     \
        eN2A = sEA; dN2A = sDA;                                               \
        eA1 = eA0v; dA1 = dA0v;                                               \
        eSelfA = newEA; dSelfA = ddLA;                                        \
        eSelfB = newEB; dSelfB = ddLB;                                        \
        PE_[ix] = newEB;                                                      \
        PD_[ix] = ddLB;                                                       \
      }

      // neighbor source: I = ebase+kk; kk even -> Even[hb+kk/2],
      // kk odd -> Odd[hb+(kk-1)/2]
      STEP(0,  mEe0.x, mDe0.x, gA0,  gB0,  pEo, pDo, 0)
      STEP(1,  mEo0.x, mDo0.x, gA1,  gB1,  pEe, pDe, 0)
      STEP(2,  mEe0.y, mDe0.y, gA2,  gB2,  pEo, pDo, 1)
      STEP(3,  mEo0.y, mDo0.y, gA3,  gB3,  pEe, pDe, 1)
      STEP(4,  mEe0.z, mDe0.z, gA4,  gB4,  pEo, pDo, 2)
      STEP(5,  mEo0.z, mDo0.z, gA5,  gB5,  pEe, pDe, 2)
      STEP(6,  mEe0.w, mDe0.w, gA6,  gB6,  pEo, pDo, 3)
      STEP(7,  mEo0.w, mDo0.w, gA7,  gB7,  pEe, pDe, 3)
      STEP(8,  mEe1.x, mDe1.x, gA8,  gB8,  pEo, pDo, 4)
      STEP(9,  mEo1.x, mDo1.x, gA9,  gB9,  pEe, pDe, 4)
      STEP(10, mEe1.y, mDe1.y, gA10, gB10, pEo, pDo, 5)
      STEP(11, mEo1.y, mDo1.y, gA11, gB11, pEe, pDe, 5)
      STEP(12, mEe1.z, mDe1.z, gA12, gB12, pEo, pDo, 6)
      STEP(13, mEo1.z, mDo1.z, gA13, gB13, pEe, pDe, 6)
      STEP(14, mEe1.w, mDe1.w, gA14, gB14, pEo, pDo, 7)
      STEP(15, mEo1.w, mDo1.w, gA15, gB15, pEe, pDe, 7)
      STEP(16, mEe2.x, mDe2.x, gA16, gB16, pEo, pDo, 8)
      STEP(17, mEo2.x, mDo2.x, gA17, gB17, pEe, pDe, 8)
      STEP(18, mEe2.y, mDe2.y, gA18, gB18, pEo, pDo, 9)
      STEP(19, mEo2.y, mDo2.y, gA19, gB19, pEe, pDe, 9)
      STEP(20, mEe2.z, mDe2.z, gA20, gB20, pEo, pDo, 10)
      STEP(21, mEo2.z, mDo2.z, gA21, gB21, pEe, pDe, 10)
      STEP(22, mEe2.w, mDe2.w, gA22, gB22, pEo, pDo, 11)
      STEP(23, mEo2.w, mDo2.w, gA23, gB23, pEe, pDe, 11)
      STEP(24, mEe3.x, mDe3.x, gA24, gB24, pEo, pDo, 12)
      STEP(25, mEo3.x, mDo3.x, gA25, gB25, pEe, pDe, 12)
      STEP(26, mEe3.y, mDe3.y, gA26, gB26, pEo, pDo, 13)
      STEP(27, mEo3.y, mDo3.y, gA27, gB27, pEe, pDe, 13)
      STEP(28, mEe3.z, mDe3.z, gA28, gB28, pEo, pDo, 14)
      STEP(29, mEo3.z, mDo3.z, gA29, gB29, pEe, pDe, 14)
      STEP(30, mEe3.w, mDe3.w, gA30, gB30, pEo, pDo, 15)
      STEP(31, mEo3.w, mDo3.w, gA31, gB31, pEe, pDe, 15)
#undef STEP
    }

    // rotate in the prefetched windows (waitcnt lands here, far from issue)
    if (dopre) {
      u0 = pu0; u1 = pu1; u2 = pu2; u3 = pu3; u4 = pu4;
      u5 = pu5; u6 = pu6; u7 = pu7; u8 = pu8;
      v0 = pv0; v1 = pv1; v2 = pv2; v3 = pv3; v4 = pv4;
      v5 = pv5; v6 = pv6; v7 = pv7; v8 = pv8;
    }
    __syncthreads();
  }
}

extern "C" void kernel_launch(void* const* d_in, const int* in_sizes, int n_in,
                              void* d_out, int out_size, void* d_ws, size_t ws_size,
                              hipStream_t stream) {
  const float* D   = (const float*)d_in[0];
  const float* Sig = (const float*)d_in[1];
  float* out = (float*)d_out;
  softdtw_fwd<<<dim3(BATCH / 2), dim3(512), 0, stream>>>(D, Sig, out);
}

// Round 5
// 264.810 us; speedup vs baseline: 1.8388x; 1.6261x over previous
//
#include <hip/hip_runtime.h>

// uDTW forward DP, R13: R11 dual-batch structure, register-dieted to fit the
// 128-VGPR budget the compiler insists on for 512-thread blocks.
//
// R12 post-mortem: amdgpu_waves_per_eu(2,2) did NOT raise the cap (VGPR_Count
// still exactly 128, WRITE_SIZE still 1.4MB of scratch). Three data points:
// 256thr -> 148 regs ok; 512thr -> capped 128 regardless of launch bounds.
// So: make the body FIT 128.
//  - no prefetch/rotate: next burst's D loads go directly into u/v AFTER the
//    steps (u/v die at the funnel); latency hides across barrier + next
//    phase's funnel. Saves 72 live regs + 72 movs/phase.
//  - neighbor preload chunked 16 quads -> 4 chunks of 4, pipelined one chunk
//    ahead (A before funnel, B after funnel, C after STEP7, D after STEP15).
//    64 -> 32 live regs; reads stay wave-uniform ds_read_b128 broadcasts.
//    w==0 reads a zeroed LDS pad (no branches at the read sites).
//  - Sig loads sunk into the final-cell branch (once, one lane): -4 regs.
// Publish: parity-split planes (R11, verified: bank conflicts = 0).
// Launch: __launch_bounds__(512, 2) -- R9's empirically-good form.

constexpr int N = 512;
constexpr int M = 512;
constexpr int BATCH = 32;
constexpr int NM = N + M;                  // 1024; diags d = 2..NM
constexpr int K = 32;                      // diagonals per burst
constexpr int NB = 32;                     // bursts cover d = 2..1025
constexpr int PHASES = NB + 3;             // 35
constexpr float NL2E = -1.4426950408889634f;   // -log2(e)
constexpr float NLN2 = -0.6931471805599453f;   // -ln(2)
constexpr float EPS  = 1e-30f;

__device__ __forceinline__ float lane_shr1_or(float oldv, float x) {
  // lane n gets lane n-1's x; lane 0 keeps oldv (bound_ctrl=false).
  return __int_as_float(__builtin_amdgcn_update_dpp(
      __float_as_int(oldv), __float_as_int(x), 0x138, 0xf, 0xf, false));
}
__device__ __forceinline__ int qclamp(int q) {
  return q < 0 ? 0 : (q > 127 ? 127 : q);
}

__global__ __launch_bounds__(512, 2)
void softdtw_fwd(const float* __restrict__ D,
                 const float* __restrict__ Sig,
                 float* __restrict__ out) {
  const int t  = threadIdx.x;          // 0..511
  const int h  = t >> 8;               // batch half 0/1
  const int tl = t & 255;              // local lane: owns rows 2tl, 2tl+1
  const int w  = tl >> 6;              // local wave 0..3
  const int b  = 2 * blockIdx.x + h;

  const float4* DrowA4 = (const float4*)(D + ((size_t)b * N + 2 * tl) * M);
  const float4* DrowB4 = (const float4*)(D + ((size_t)b * N + 2 * tl + 1) * M);

  // boundary planes, split by column parity. Original index I = 128 + c
  // (c = j-1, 128-halo). I odd -> *Odd[(I-1)/2], I even -> *Even[I/2].
  __shared__ float eOdd [2][4][384];
  __shared__ float eEven[2][4][384];
  __shared__ float dOdd [2][4][384];
  __shared__ float dEven[2][4][384];
  __shared__ __align__(16) float zpad[64];   // zero source for w==0 reads
  {
    float* z0 = &eOdd[0][0][0];  float* z1 = &eEven[0][0][0];
    float* z2 = &dOdd[0][0][0];  float* z3 = &dEven[0][0][0];
    for (int idx = t; idx < 2 * 4 * 384; idx += 512) {
      z0[idx] = 0.f; z1[idx] = 0.f; z2[idx] = 0.f; z3[idx] = 0.f;
    }
    if (t < 64) zpad[t] = 0.f;
  }

  // carried state (D values pre-scaled by NL2E; carried/published raw,
  // consumers multiply by masked-zero E)
  float eSelfA = 0.f, dSelfA = 0.f;            // row A at prev diag
  float eA1 = 0.f, dA1 = 0.f;                  // row A, one step further back
  float eN2A = (tl == 0) ? 1.f : 0.f;          // neighbor (i-1) at d-2; E(0,0)=1
  float dN2A = 0.f;
  float eSelfB = 0.f, dSelfB = 0.f;            // row B at prev diag

  const int Bl = 4 * w, Bh = 4 * w + 19;   // active bursts for this wave
  const bool sA2 = (tl & 1) != 0;          // row-A funnel: shift {0,2}
  const bool sB2 = (tl & 1) == 0;          // row-B funnel: shift {1,3}

  // current-burst D windows: 9 quads per row (loaded for burst Bl here;
  // refreshed in-place at the END of each phase for the next burst)
  float4 u0,u1,u2,u3,u4,u5,u6,u7,u8;       // row A
  float4 v0,v1,v2,v3,v4,v5,v6,v7,v8;       // row B
  {
    const int qa = (32 * Bl - 2 * tl) >> 2;
    u0 = DrowA4[qclamp(qa + 0)]; u1 = DrowA4[qclamp(qa + 1)];
    u2 = DrowA4[qclamp(qa + 2)]; u3 = DrowA4[qclamp(qa + 3)];
    u4 = DrowA4[qclamp(qa + 4)]; u5 = DrowA4[qclamp(qa + 5)];
    u6 = DrowA4[qclamp(qa + 6)]; u7 = DrowA4[qclamp(qa + 7)];
    u8 = DrowA4[qclamp(qa + 8)];
    const int qb = (32 * Bl - 2 * tl - 1) >> 2;
    v0 = DrowB4[qclamp(qb + 0)]; v1 = DrowB4[qclamp(qb + 1)];
    v2 = DrowB4[qclamp(qb + 2)]; v3 = DrowB4[qclamp(qb + 3)];
    v4 = DrowB4[qclamp(qb + 4)]; v5 = DrowB4[qclamp(qb + 5)];
    v6 = DrowB4[qclamp(qb + 6)]; v7 = DrowB4[qclamp(qb + 7)];
    v8 = DrowB4[qclamp(qb + 8)];
  }
  __syncthreads();

  for (int p = 0; p < PHASES; ++p) {
    const int B = p - w;
    const int nB = B + 1;
    const bool dopre = (nB >= Bl) && (nB <= Bh);   // wave-uniform

    if (B >= Bl && B <= Bh) {
      const int d0 = 2 + B * K;
      const int cA0 = 32 * B - 2 * tl;   // row-A column index base (c = j-1)

      // ---- neighbor boundary plane pointers (wave-uniform). Need E[I],D[I]
      // for I = ebase..ebase+31, ebase = 32B-128w+128 (even); per parity
      // plane that is 4 quads starting at hb = ebase/2 (16B-aligned).
      // w==0 reads the zeroed pad instead (branch-free read sites).
      const float4 *pe, *po, *qe, *qo;
      if (w > 0) {
        const int hb = 16 * B - 64 * w + 64;
        pe = (const float4*)&eEven[h][w - 1][hb];
        po = (const float4*)&eOdd [h][w - 1][hb];
        qe = (const float4*)&dEven[h][w - 1][hb];
        qo = (const float4*)&dOdd [h][w - 1][hb];
      } else {
        pe = po = qe = qo = (const float4*)zpad;
      }

      // chunk A (steps 0..7), read ahead of the funnel
      const float4 nEeA = pe[0], nEoA = po[0], nDeA = qe[0], nDoA = qo[0];

      // ---- unpack windows
      const float
        A0=u0.x, A1=u0.y, A2=u0.z, A3=u0.w,  A4=u1.x, A5=u1.y, A6=u1.z, A7=u1.w,
        A8=u2.x, A9=u2.y, A10=u2.z, A11=u2.w, A12=u3.x, A13=u3.y, A14=u3.z, A15=u3.w,
        A16=u4.x, A17=u4.y, A18=u4.z, A19=u4.w, A20=u5.x, A21=u5.y, A22=u5.z, A23=u5.w,
        A24=u6.x, A25=u6.y, A26=u6.z, A27=u6.w, A28=u7.x, A29=u7.y, A30=u7.z, A31=u7.w,
        A32=u8.x, A33=u8.y;
      const float
        F1=v0.y, F2=v0.z, F3=v0.w,  F4=v1.x, F5=v1.y, F6=v1.z, F7=v1.w,
        F8=v2.x, F9=v2.y, F10=v2.z, F11=v2.w, F12=v3.x, F13=v3.y, F14=v3.z, F15=v3.w,
        F16=v4.x, F17=v4.y, F18=v4.z, F19=v4.w, F20=v5.x, F21=v5.y, F22=v5.z, F23=v5.w,
        F24=v6.x, F25=v6.y, F26=v6.z, F27=v6.w, F28=v7.x, F29=v7.y, F30=v7.z, F31=v7.w,
        F32=v8.x, F33=v8.y, F34=v8.z;

      // ---- funnel align: gA_k = D_A[cA0+k], gB_k = D_B[cA0-1+k]
      const float
        gA0 =sA2?A2 :A0,  gA1 =sA2?A3 :A1,  gA2 =sA2?A4 :A2,  gA3 =sA2?A5 :A3,
        gA4 =sA2?A6 :A4,  gA5 =sA2?A7 :A5,  gA6 =sA2?A8 :A6,  gA7 =sA2?A9 :A7,
        gA8 =sA2?A10:A8,  gA9 =sA2?A11:A9,  gA10=sA2?A12:A10, gA11=sA2?A13:A11,
        gA12=sA2?A14:A12, gA13=sA2?A15:A13, gA14=sA2?A16:A14, gA15=sA2?A17:A15,
        gA16=sA2?A18:A16, gA17=sA2?A19:A17, gA18=sA2?A20:A18, gA19=sA2?A21:A19,
        gA20=sA2?A22:A20, gA21=sA2?A23:A21, gA22=sA2?A24:A22, gA23=sA2?A25:A23,
        gA24=sA2?A26:A24, gA25=sA2?A27:A25, gA26=sA2?A28:A26, gA27=sA2?A29:A27,
        gA28=sA2?A30:A28, gA29=sA2?A31:A29, gA30=sA2?A32:A30, gA31=sA2?A33:A31;
      const float
        gB0 =sB2?F3 :F1,  gB1 =sB2?F4 :F2,  gB2 =sB2?F5 :F3,  gB3 =sB2?F6 :F4,
        gB4 =sB2?F7 :F5,  gB5 =sB2?F8 :F6,  gB6 =sB2?F9 :F7,  gB7 =sB2?F10:F8,
        gB8 =sB2?F11:F9,  gB9 =sB2?F12:F10, gB10=sB2?F13:F11, gB11=sB2?F14:F12,
        gB12=sB2?F15:F13, gB13=sB2?F16:F14, gB14=sB2?F17:F15, gB15=sB2?F18:F16,
        gB16=sB2?F19:F17, gB17=sB2?F20:F18, gB18=sB2?F21:F19, gB19=sB2?F22:F20,
        gB20=sB2?F23:F21, gB21=sB2?F24:F22, gB22=sB2?F25:F23, gB23=sB2?F26:F24,
        gB24=sB2?F27:F25, gB25=sB2?F28:F26, gB26=sB2?F29:F27, gB27=sB2?F30:F28,
        gB28=sB2?F31:F29, gB29=sB2?F32:F30, gB30=sB2?F33:F31, gB31=sB2?F34:F32;

      // chunk B (steps 8..15), read behind the funnel, ahead of the steps
      const float4 nEeB = pe[1], nEoB = po[1], nDeB = qe[1], nDoB = qo[1];

      // publish pointers: stored column c = cA0-1+kk, I = 128+c.
      // kk even -> I odd  -> *Odd [63 + 16B - tl + kk/2]
      // kk odd  -> I even -> *Even[64 + 16B - tl + (kk-1)/2]
      // lane stride -4B per plane => 2 lanes/bank = conflict-free.
      const int sb = 16 * B - tl;
      float* pEo = &eOdd [h][w][63 + sb];
      float* pEe = &eEven[h][w][64 + sb];
      float* pDo = &dOdd [h][w][63 + sb];
      float* pDe = &dEven[h][w][64 + sb];

#define STEP(kk, NEv, NDv, GA, GB, PE_, PD_, ix)                              \
      {                                                                       \
        const float eA0v = eSelfA, dA0v = dSelfA;                             \
        const float eB0v = eSelfB, dB0v = dSelfB;                             \
        const int cA = cA0 + (kk);                                            \
        const float ddLA = (GA) * NL2E;                                       \
        const float ddLAm = ((unsigned)cA < 512u) ? ddLA : -1e30f;            \
        const float ddLB = (GB) * NL2E;                                       \
        const float ddLBm = ((unsigned)(cA - 1) < 512u) ? ddLB : -1e30f;      \
        const float sEA = lane_shr1_or((NEv), eB0v);                          \
        const float sDA = lane_shr1_or((NDv), dB0v);                          \
        const float sumA = ((eN2A + eA0v) + EPS) + sEA;                       \
        const float invA = __builtin_amdgcn_rcpf(sumA);                       \
        const float numA = fmaf(eN2A, dN2A, fmaf(sEA, sDA, eA0v * dA0v));     \
        const float rrA = fmaf(invA, numA, ddLAm);                            \
        const float newEA = __builtin_amdgcn_exp2f(rrA);                      \
        const float sumB = ((eA1 + eB0v) + EPS) + eA0v;                       \
        const float invB = __builtin_amdgcn_rcpf(sumB);                       \
        const float numB = fmaf(eA1, dA1, fmaf(eA0v, dA0v, eB0v * dB0v));     \
        const float rrB = fmaf(invB, numB, ddLBm);                            \
        const float newEB = __builtin_amdgcn_exp2f(rrB);                      \
        if (d0 + (kk) == NM && tl == 255) {                                   \
          const float* Sb = Sig + (size_t)b * N * M;                          \
          const float sgA = Sb[(size_t)(N - 1) * M + (M - 1)];                \
          const float sg0 = Sb[(size_t)(N - 2) * M + (M - 2)];                \
          const float sg1 = Sb[(size_t)(N - 2) * M + (M - 1)];                \
          const float sg2 = Sb[(size_t)(N - 1) * M + (M - 2)];                \
          out[b] = rrB * NLN2;                                                \
          out[BATCH + b] = sgA + invB * (eA1 * sg0 + eA0v * sg1 + eB0v * sg2);\
        }                                                                     \
        eN2A = sEA; dN2A = sDA;                                               \
        eA1 = eA0v; dA1 = dA0v;                                               \
        eSelfA = newEA; dSelfA = ddLA;                                        \
        eSelfB = newEB; dSelfB = ddLB;                                        \
        PE_[ix] = newEB;                                                      \
        PD_[ix] = ddLB;                                                       \
      }

      // neighbor source: I = ebase+kk; kk even -> Even-plane quad kk/8,
      // component (kk/2)%4; kk odd -> Odd-plane same quad/component.
      STEP(0,  nEeA.x, nDeA.x, gA0,  gB0,  pEo, pDo, 0)
      STEP(1,  nEoA.x, nDoA.x, gA1,  gB1,  pEe, pDe, 0)
      STEP(2,  nEeA.y, nDeA.y, gA2,  gB2,  pEo, pDo, 1)
      STEP(3,  nEoA.y, nDoA.y, gA3,  gB3,  pEe, pDe, 1)
      STEP(4,  nEeA.z, nDeA.z, gA4,  gB4,  pEo, pDo, 2)
      STEP(5,  nEoA.z, nDoA.z, gA5,  gB5,  pEe, pDe, 2)
      STEP(6,  nEeA.w, nDeA.w, gA6,  gB6,  pEo, pDo, 3)
      STEP(7,  nEoA.w, nDoA.w, gA7,  gB7,  pEe, pDe, 3)

      // chunk C (steps 16..23)
      const float4 nEeC = pe[2], nEoC = po[2], nDeC = qe[2], nDoC = qo[2];

      STEP(8,  nEeB.x, nDeB.x, gA8,  gB8,  pEo, pDo, 4)
      STEP(9,  nEoB.x, nDoB.x, gA9,  gB9,  pEe, pDe, 4)
      STEP(10, nEeB.y, nDeB.y, gA10, gB10, pEo, pDo, 5)
      STEP(11, nEoB.y, nDoB.y, gA11, gB11, pEe, pDe, 5)
      STEP(12, nEeB.z, nDeB.z, gA12, gB12, pEo, pDo, 6)
      STEP(13, nEoB.z, nDoB.z, gA13, gB13, pEe, pDe, 6)
      STEP(14, nEeB.w, nDeB.w, gA14, gB14, pEo, pDo, 7)
      STEP(15, nEoB.w, nDoB.w, gA15, gB15, pEe, pDe, 7)

      // chunk D (steps 24..31)
      const float4 nEeD = pe[3], nEoD = po[3], nDeD = qe[3], nDoD = qo[3];

      STEP(16, nEeC.x, nDeC.x, gA16, gB16, pEo, pDo, 8)
      STEP(17, nEoC.x, nDoC.x, gA17, gB17, pEe, pDe, 8)
      STEP(18, nEeC.y, nDeC.y, gA18, gB18, pEo, pDo, 9)
      STEP(19, nEoC.y, nDoC.y, gA19, gB19, pEe, pDe, 9)
      STEP(20, nEeC.z, nDeC.z, gA20, gB20, pEo, pDo, 10)
      STEP(21, nEoC.z, nDoC.z, gA21, gB21, pEe, pDe, 10)
      STEP(22, nEeC.w, nDeC.w, gA22, gB22, pEo, pDo, 11)
      STEP(23, nEoC.w, nDoC.w, gA23, gB23, pEe, pDe, 11)

      STEP(24, nEeD.x, nDeD.x, gA24, gB24, pEo, pDo, 12)
      STEP(25, nEoD.x, nDoD.x, gA25, gB25, pEe, pDe, 12)
      STEP(26, nEeD.y, nDeD.y, gA26, gB26, pEo, pDo, 13)
      STEP(27, nEoD.y, nDoD.y, gA27, gB27, pEe, pDe, 13)
      STEP(28, nEeD.z, nDeD.z, gA28, gB28, pEo, pDo, 14)
      STEP(29, nEoD.z, nDoD.z, gA29, gB29, pEe, pDe, 14)
      STEP(30, nEeD.w, nDeD.w, gA30, gB30, pEo, pDo, 15)
      STEP(31, nEoD.w, nDoD.w, gA31, gB31, pEe, pDe, 15)
#undef STEP
    }

    // ---- load next burst's window directly into u/v (they died at the
    // funnel). Latency hides across the barrier + next phase's funnel.
    if (dopre) {
      const int qa = (32 * nB - 2 * tl) >> 2;
      u0 = DrowA4[qclamp(qa + 0)]; u1 = DrowA4[qclamp(qa + 1)];
      u2 = DrowA4[qclamp(qa + 2)]; u3 = DrowA4[qclamp(qa + 3)];
      u4 = DrowA4[qclamp(qa + 4)]; u5 = DrowA4[qclamp(qa + 5)];
      u6 = DrowA4[qclamp(qa + 6)]; u7 = DrowA4[qclamp(qa + 7)];
      u8 = DrowA4[qclamp(qa + 8)];
      const int qb = (32 * nB - 2 * tl - 1) >> 2;
      v0 = DrowB4[qclamp(qb + 0)]; v1 = DrowB4[qclamp(qb + 1)];
      v2 = DrowB4[qclamp(qb + 2)]; v3 = DrowB4[qclamp(qb + 3)];
      v4 = DrowB4[qclamp(qb + 4)]; v5 = DrowB4[qclamp(qb + 5)];
      v6 = DrowB4[qclamp(qb + 6)]; v7 = DrowB4[qclamp(qb + 7)];
      v8 = DrowB4[qclamp(qb + 8)];
    }
    __syncthreads();
  }
}

extern "C" void kernel_launch(void* const* d_in, const int* in_sizes, int n_in,
                              void* d_out, int out_size, void* d_ws, size_t ws_size,
                              hipStream_t stream) {
  const float* D   = (const float*)d_in[0];
  const float* Sig = (const float*)d_in[1];
  float* out = (float*)d_out;
  softdtw_fwd<<<dim3(BATCH / 2), dim3(512), 0, stream>>>(D, Sig, out);
}

// Round 6
// 177.806 us; speedup vs baseline: 2.7386x; 1.4893x over previous
//
#include <hip/hip_runtime.h>

// uDTW forward DP, R14: R9 structure (proven 120us: 512thr, 8 waves, 1
// row/lane, K=32, 39 phases, float2 edge publish, DPP boundary fold,
// masked-log2 validity) with the register-diet techniques R13 proved:
//  - NO prefetch double-buffer: r0..r8 die at the funnel, so next burst's
//    loads go directly into them right after the funnel; the ~600-inst step
//    region hides the latency before the barrier drain. -36 live regs,
//    -72 movs/phase vs R9.
//  - neighbor preload chunked 16 -> 4x4 float4, pipelined through the steps
//    (wave-uniform ds_read_b128 broadcasts; zeroed LDS pad for w==0 makes
//    read sites branch-free). -32 live regs.
//  - Sig loads sunk into the once-executed final-cell branch. -4 regs.
// R11-R13 lesson recorded: dual-batch-per-block halves active CUs at fixed
// total work -> 2x per-phase cost (16.1k vs 7.4k cyc). Never again.

constexpr int N = 512;
constexpr int M = 512;
constexpr int BATCH = 32;
constexpr int NM = N + M;                  // 1024; diags d = 2..NM
constexpr int K = 32;                      // diagonals per burst
constexpr int NB = 32;                     // bursts cover d = 2..1025
constexpr int PHASES = NB + 7;             // 39
constexpr float NL2E = -1.4426950408889634f;   // -log2(e)
constexpr float NLN2 = -0.6931471805599453f;   // -ln(2)
constexpr float EPS  = 1e-30f;

__device__ __forceinline__ float lane_shr1_or(float oldv, float x) {
  // lane n gets lane n-1's x; lane 0 keeps oldv (bound_ctrl=false).
  return __int_as_float(__builtin_amdgcn_update_dpp(
      __float_as_int(oldv), __float_as_int(x), 0x138, 0xf, 0xf, false));
}
__device__ __forceinline__ int qclamp(int q) {
  return q < 0 ? 0 : (q > 127 ? 127 : q);
}

__global__ __launch_bounds__(512, 2)
void softdtw_fwd(const float* __restrict__ D,
                 const float* __restrict__ Sig,
                 float* __restrict__ out) {
  const int b = blockIdx.x;
  const int t = threadIdx.x;           // row r = t, cell i = t+1
  const int w = t >> 6;                // wave 0..7
  const float4* Drow4 = (const float4*)(D + ((size_t)b * N + t) * M);

  // edge[w][64 + c] = (exp(-R), NL2E*Ddiag) of row 64w+63 at column c.
  __shared__ float2 edge[8][640];
  __shared__ __align__(16) float zpad[64];   // zero source for w==0 reads
  for (int idx = t; idx < 8 * 640; idx += 512)
    ((float2*)edge)[idx] = make_float2(0.f, 0.f);
  if (t < 64) zpad[t] = 0.f;

  // carried state: own cell at d-1, neighbor (i-1) at d-2 (D pre-scaled)
  float eSelf = 0.f, dSelfL = 0.f;
  float eN2 = (t == 0) ? 1.f : 0.f, dN2L = 0.f;   // R[0,0]=0 -> e=1

  const int Bl = 2 * w, Bh = 2 * w + 17;   // active bursts for this wave

  // current-burst D window: 9 quads covering floats [4*((32B-t)>>2), +36)
  float4 r0, r1, r2, r3, r4, r5, r6, r7, r8;
  {
    const int q = (32 * Bl - t) >> 2;
    r0 = Drow4[qclamp(q + 0)]; r1 = Drow4[qclamp(q + 1)];
    r2 = Drow4[qclamp(q + 2)]; r3 = Drow4[qclamp(q + 3)];
    r4 = Drow4[qclamp(q + 4)]; r5 = Drow4[qclamp(q + 5)];
    r6 = Drow4[qclamp(q + 6)]; r7 = Drow4[qclamp(q + 7)];
    r8 = Drow4[qclamp(q + 8)];
  }
  __syncthreads();

  for (int p = 0; p < PHASES; ++p) {
    const int B = p - w;
    const int nB = B + 1;
    const bool dopre = (nB >= Bl) && (nB <= Bh);   // wave-uniform

    if (B >= Bl && B <= Bh) {
      const int d0 = 2 + B * K;
      const int c0 = d0 - t - 2;       // = 32B - t; in [-63, 544]

      // ---- neighbor boundary plane pointer (wave-uniform, branch-free
      // read sites; w==0 reads the zeroed pad: 16 float4 = 64 floats)
      const float4* ep = (w > 0)
          ? (const float4*)&edge[w - 1][64 + (d0 - 64 * w - 2)]
          : (const float4*)zpad;

      // chunk A (steps 0..7)
      const float4 n0 = ep[0], n1 = ep[1], n2 = ep[2], n3 = ep[3];

      // ---- funnel align by s = c0 & 3: g_e = D[c0 + e], e in [0,32)
      const int s = c0 & 3;
      const bool s2 = (s & 2) != 0, s1b = (s & 1) != 0;
      const float
        f0 = r0.x, f1 = r0.y, f2 = r0.z, f3 = r0.w,
        f4 = r1.x, f5 = r1.y, f6 = r1.z, f7 = r1.w,
        f8 = r2.x, f9 = r2.y, f10 = r2.z, f11 = r2.w,
        f12 = r3.x, f13 = r3.y, f14 = r3.z, f15 = r3.w,
        f16 = r4.x, f17 = r4.y, f18 = r4.z, f19 = r4.w,
        f20 = r5.x, f21 = r5.y, f22 = r5.z, f23 = r5.w,
        f24 = r6.x, f25 = r6.y, f26 = r6.z, f27 = r6.w,
        f28 = r7.x, f29 = r7.y, f30 = r7.z, f31 = r7.w,
        f32 = r8.x, f33 = r8.y, f34 = r8.z, f35 = r8.w;
      const float
        x0  = s2 ? f2  : f0,  x1  = s2 ? f3  : f1,  x2  = s2 ? f4  : f2,
        x3  = s2 ? f5  : f3,  x4  = s2 ? f6  : f4,  x5  = s2 ? f7  : f5,
        x6  = s2 ? f8  : f6,  x7  = s2 ? f9  : f7,  x8  = s2 ? f10 : f8,
        x9  = s2 ? f11 : f9,  x10 = s2 ? f12 : f10, x11 = s2 ? f13 : f11,
        x12 = s2 ? f14 : f12, x13 = s2 ? f15 : f13, x14 = s2 ? f16 : f14,
        x15 = s2 ? f17 : f15, x16 = s2 ? f18 : f16, x17 = s2 ? f19 : f17,
        x18 = s2 ? f20 : f18, x19 = s2 ? f21 : f19, x20 = s2 ? f22 : f20,
        x21 = s2 ? f23 : f21, x22 = s2 ? f24 : f22, x23 = s2 ? f25 : f23,
        x24 = s2 ? f26 : f24, x25 = s2 ? f27 : f25, x26 = s2 ? f28 : f26,
        x27 = s2 ? f29 : f27, x28 = s2 ? f30 : f28, x29 = s2 ? f31 : f29,
        x30 = s2 ? f32 : f30, x31 = s2 ? f33 : f31, x32 = s2 ? f34 : f32;
      const float
        g0  = s1b ? x1  : x0,  g1  = s1b ? x2  : x1,  g2  = s1b ? x3  : x2,
        g3  = s1b ? x4  : x3,  g4  = s1b ? x5  : x4,  g5  = s1b ? x6  : x5,
        g6  = s1b ? x7  : x6,  g7  = s1b ? x8  : x7,  g8  = s1b ? x9  : x8,
        g9  = s1b ? x10 : x9,  g10 = s1b ? x11 : x10, g11 = s1b ? x12 : x11,
        g12 = s1b ? x13 : x12, g13 = s1b ? x14 : x13, g14 = s1b ? x15 : x14,
        g15 = s1b ? x16 : x15, g16 = s1b ? x17 : x16, g17 = s1b ? x18 : x17,
        g18 = s1b ? x19 : x18, g19 = s1b ? x20 : x19, g20 = s1b ? x21 : x20,
        g21 = s1b ? x22 : x21, g22 = s1b ? x23 : x22, g23 = s1b ? x24 : x23,
        g24 = s1b ? x25 : x24, g25 = s1b ? x26 : x25, g26 = s1b ? x27 : x26,
        g27 = s1b ? x28 : x27, g28 = s1b ? x29 : x28, g29 = s1b ? x30 : x29,
        g30 = s1b ? x31 : x30, g31 = s1b ? x32 : x31;

      // ---- r0..r8 are dead now: issue next burst's loads into them; the
      // 32 steps below (~600 inst) hide the latency before the barrier.
      if (dopre) {
        const int q = (32 * nB - t) >> 2;
        r0 = Drow4[qclamp(q + 0)]; r1 = Drow4[qclamp(q + 1)];
        r2 = Drow4[qclamp(q + 2)]; r3 = Drow4[qclamp(q + 3)];
        r4 = Drow4[qclamp(q + 4)]; r5 = Drow4[qclamp(q + 5)];
        r6 = Drow4[qclamp(q + 6)]; r7 = Drow4[qclamp(q + 7)];
        r8 = Drow4[qclamp(q + 8)];
      }

      // chunk B (steps 8..15)
      const float4 n4 = ep[4], n5 = ep[5], n6 = ep[6], n7 = ep[7];

      float2* eput = &edge[w][64 + c0];   // write-once publish (8B stride)

#define STEP(kk, NE, ND)                                                       \
      {                                                                        \
        const int c = c0 + (kk);                                               \
        const bool valid = ((unsigned)c) < 512u;                               \
        const float ddL = (g##kk) * NL2E;                                      \
        const float ddLm = valid ? ddL : -1e30f;                               \
        const float sE = lane_shr1_or((NE), eSelf);                            \
        const float sD = lane_shr1_or((ND), dSelfL);                           \
        const float e0 = eN2, e2 = eSelf;                                      \
        const float s02 = (e0 + e2) + EPS;                                     \
        const float sum = s02 + sE;                                            \
        const float inv = __builtin_amdgcn_rcpf(sum);                          \
        const float numL = fmaf(e0, dN2L, fmaf(sE, sD, e2 * dSelfL));          \
        const float rr = fmaf(inv, numL, ddLm);                                \
        const float newE = __builtin_amdgcn_exp2f(rr);                         \
        if (d0 + (kk) == NM && t == N - 1) {                                   \
          const float* Sb = Sig + (size_t)b * N * M;                           \
          const float sgA = Sb[(size_t)(N - 1) * M + (M - 1)];                 \
          const float sg0 = Sb[(size_t)(N - 2) * M + (M - 2)];                 \
          const float sg1 = Sb[(size_t)(N - 2) * M + (M - 1)];                 \
          const float sg2 = Sb[(size_t)(N - 1) * M + (M - 2)];                 \
          out[b] = rr * NLN2;                                                  \
          out[BATCH + b] = sgA + inv * (e0 * sg0 + sE * sg1 + e2 * sg2);       \
        }                                                                      \
        eN2 = sE; dN2L = sD;                                                   \
        eSelf = newE; dSelfL = ddL;                                            \
        eput[kk] = make_float2(newE, ddL);                                     \
      }
#define STEP2(m, NQ)                                                           \
      STEP(2 * m,     NQ.x, NQ.y)                                              \
      STEP(2 * m + 1, NQ.z, NQ.w)

      // Gk bound via g##kk inside STEP; expand pairs explicitly:
      STEP(0,  n0.x, n0.y)  STEP(1,  n0.z, n0.w)
      STEP(2,  n1.x, n1.y)  STEP(3,  n1.z, n1.w)
      STEP(4,  n2.x, n2.y)  STEP(5,  n2.z, n2.w)
      STEP(6,  n3.x, n3.y)  STEP(7,  n3.z, n3.w)

      // chunk C (steps 16..23)
      const float4 n8 = ep[8], n9 = ep[9], n10 = ep[10], n11 = ep[11];

      STEP(8,  n4.x, n4.y)  STEP(9,  n4.z, n4.w)
      STEP(10, n5.x, n5.y)  STEP(11, n5.z, n5.w)
      STEP(12, n6.x, n6.y)  STEP(13, n6.z, n6.w)
      STEP(14, n7.x, n7.y)  STEP(15, n7.z, n7.w)

      // chunk D (steps 24..31)
      const float4 n12 = ep[12], n13 = ep[13], n14 = ep[14], n15 = ep[15];

      STEP(16, n8.x,  n8.y)   STEP(17, n8.z,  n8.w)
      STEP(18, n9.x,  n9.y)   STEP(19, n9.z,  n9.w)
      STEP(20, n10.x, n10.y)  STEP(21, n10.z, n10.w)
      STEP(22, n11.x, n11.y)  STEP(23, n11.z, n11.w)

      STEP(24, n12.x, n12.y)  STEP(25, n12.z, n12.w)
      STEP(26, n13.x, n13.y)  STEP(27, n13.z, n13.w)
      STEP(28, n14.x, n14.y)  STEP(29, n14.z, n14.w)
      STEP(30, n15.x, n15.y)  STEP(31, n15.z, n15.w)
#undef STEP2
#undef STEP
    } else if (dopre) {
      // pipeline-fill: wave becomes active next phase; load its first burst
      const int q = (32 * nB - t) >> 2;
      r0 = Drow4[qclamp(q + 0)]; r1 = Drow4[qclamp(q + 1)];
      r2 = Drow4[qclamp(q + 2)]; r3 = Drow4[qclamp(q + 3)];
      r4 = Drow4[qclamp(q + 4)]; r5 = Drow4[qclamp(q + 5)];
      r6 = Drow4[qclamp(q + 6)]; r7 = Drow4[qclamp(q + 7)];
      r8 = Drow4[qclamp(q + 8)];
    }

    __syncthreads();
  }
}

extern "C" void kernel_launch(void* const* d_in, const int* in_sizes, int n_in,
                              void* d_out, int out_size, void* d_ws, size_t ws_size,
                              hipStream_t stream) {
  const float* D   = (const float*)d_in[0];
  const float* Sig = (const float*)d_in[1];
  float* out = (float*)d_out;
  softdtw_fwd<<<dim3(BATCH), dim3(512), 0, stream>>>(D, Sig, out);
}